// Round 1
// baseline (270.152 us; speedup 1.0000x reference)
//
#include <hip/hip_runtime.h>
#include <stdint.h>

// Problem constants
#define ROWS  16384   // B*T = 512*32
#define CELL  128
#define INF   512     // input features
#define TPB   256     // 4 waves
#define RPB   16      // rows per block
#define NSTEP 32

typedef short bf16x8 __attribute__((ext_vector_type(8)));
typedef float f32x4  __attribute__((ext_vector_type(4)));

#define MFMA(a, b, c) __builtin_amdgcn_mfma_f32_16x16x32_bf16((a), (b), (c), 0, 0, 0)

// ws layout (ushort elems):
//   A_sw[g]  at g*16384          (g=0..3: Wf,Wi1,Wi2,Wo rows 0..127 -> cell part)
//   Xw_sw[g] at 65536 + g*65536  (rows 128..639 -> x part)
//   Wc_sw    at 327680
#define AOFF  0
#define XOFF  65536
#define WCOFF 327680
#define WSTOT 344064

__device__ __forceinline__ unsigned short f2bf(float f) {
  uint32_t u = __float_as_uint(f);
  uint32_t r = u + 0x7FFF + ((u >> 16) & 1);   // RNE truncate to bf16
  return (unsigned short)(r >> 16);
}
__device__ __forceinline__ float bf2f(unsigned short h) {
  return __uint_as_float(((uint32_t)h) << 16);
}
__device__ __forceinline__ float sig_f(float z) {
  return __builtin_amdgcn_rcpf(1.f + __expf(-z));
}
__device__ __forceinline__ float tanh_f(float z) {
  return 1.f - 2.f * __builtin_amdgcn_rcpf(__expf(2.f * z) + 1.f);
}

// Swizzle weights to bf16 MFMA B-fragment order:
// dst[((kb*8+nb)*64 + lane)*8 + j] = W[kb*32 + (lane>>4)*8 + j][nb*16 + (lane&15)]
__global__ __launch_bounds__(256) void prep_kernel(
    const float* __restrict__ Wf, const float* __restrict__ Wi1,
    const float* __restrict__ Wi2, const float* __restrict__ Wo,
    const float* __restrict__ Wc, unsigned short* __restrict__ ws) {
  int id = blockIdx.x * blockDim.x + threadIdx.x;
  if (id >= WSTOT) return;
  const float* Wg[4] = {Wf, Wi1, Wi2, Wo};
  if (id < XOFF) {                       // cell-part A matrices (k = 0..127)
    int g = id >> 14, r = id & 16383;
    int j = r & 7, lane = (r >> 3) & 63, nb = (r >> 9) & 7, kb = r >> 12;
    int k = kb * 32 + ((lane >> 4) << 3) + j;
    int n = nb * 16 + (lane & 15);
    ws[id] = f2bf(Wg[g][k * CELL + n]);
  } else if (id < WCOFF) {               // x-part (k = 0..511, W row 128+k)
    int t = id - XOFF;
    int g = t >> 16, r = t & 65535;
    int j = r & 7, lane = (r >> 3) & 63, nb = (r >> 9) & 7, kb = r >> 12;
    int k = kb * 32 + ((lane >> 4) << 3) + j;
    int n = nb * 16 + (lane & 15);
    ws[id] = f2bf(Wg[g][(CELL + k) * CELL + n]);
  } else {                               // Wc [128][128]
    int r = id - WCOFF;
    int j = r & 7, lane = (r >> 3) & 63, nb = (r >> 9) & 7, kb = r >> 12;
    int k = kb * 32 + ((lane >> 4) << 3) + j;
    int n = nb * 16 + (lane & 15);
    ws[id] = f2bf(Wc[k * CELL + n]);
  }
}

__global__ __launch_bounds__(256) void lstm_kernel(
    const float* __restrict__ x,
    const float* __restrict__ bf_, const float* __restrict__ bi1,
    const float* __restrict__ bi2, const float* __restrict__ bo,
    const float* __restrict__ bc,
    const unsigned short* __restrict__ ws, float* __restrict__ out) {

  // LDS: x staging (hi/lo) reused later by epilogue (o bf16 + s f32);
  // c double-buffered bf16 hi/lo, padded row stride 136 (272B, 16B aligned).
  __shared__ union {
    unsigned short xs[2][16][520];              // [hi/lo][row][512+8]
    struct {
      unsigned short o[16][136];
      float          s[16][132];
    } ep;
  } uS;
  __shared__ unsigned short cHi[2][16][136];
  __shared__ unsigned short cLo[2][16][136];

  const int tid  = threadIdx.x;
  const int lane = tid & 63;
  const int w    = tid >> 6;     // wave 0..3, owns cols [w*32, w*32+32)
  const int q    = lane >> 4;    // 0..3
  const int tn   = lane & 15;
  const int r0   = blockIdx.x * RPB;

  const unsigned short* Asw  = ws + AOFF;
  const unsigned short* Xsw  = ws + XOFF;
  const unsigned short* Wcsw = ws + WCOFF;

  // ---------------- stage x -> LDS as bf16 hi/lo ----------------
#pragma unroll
  for (int i = 0; i < 8; ++i) {
    int flat = tid + i * 256;            // 2048 float4 slots = 16 rows * 128
    int row = flat >> 7, c4 = flat & 127;
    const float4 v = ((const float4*)(x + (size_t)(r0 + row) * INF))[c4];
    unsigned short h0 = f2bf(v.x), h1 = f2bf(v.y), h2 = f2bf(v.z), h3 = f2bf(v.w);
    unsigned short l0 = f2bf(v.x - bf2f(h0)), l1 = f2bf(v.y - bf2f(h1));
    unsigned short l2 = f2bf(v.z - bf2f(h2)), l3 = f2bf(v.w - bf2f(h3));
    *(ushort4*)&uS.xs[0][row][c4 * 4] = make_ushort4(h0, h1, h2, h3);
    *(ushort4*)&uS.xs[1][row][c4 * 4] = make_ushort4(l0, l1, l2, l3);
  }
  __syncthreads();

  // ---------------- precompute u_g = x @ Wg[128:,:] + b_g ----------------
  f32x4 uacc[4][2];
#pragma unroll
  for (int g = 0; g < 4; ++g)
#pragma unroll
    for (int t2 = 0; t2 < 2; ++t2) uacc[g][t2] = (f32x4){0.f, 0.f, 0.f, 0.f};

#pragma unroll 4
  for (int kb = 0; kb < 16; ++kb) {
    bf16x8 ah = *(const bf16x8*)&uS.xs[0][tn][kb * 32 + q * 8];
    bf16x8 al = *(const bf16x8*)&uS.xs[1][tn][kb * 32 + q * 8];
#pragma unroll
    for (int g = 0; g < 4; ++g) {
#pragma unroll
      for (int t2 = 0; t2 < 2; ++t2) {
        int nb = w * 2 + t2;
        bf16x8 b = *(const bf16x8*)(Xsw + g * 65536 + ((kb * 8 + nb) * 64 + lane) * 8);
        uacc[g][t2] = MFMA(ah, b, uacc[g][t2]);
        uacc[g][t2] = MFMA(al, b, uacc[g][t2]);
      }
    }
  }
  {
    const float* bias[4] = {bf_, bi1, bi2, bo};
#pragma unroll
    for (int g = 0; g < 4; ++g)
#pragma unroll
      for (int t2 = 0; t2 < 2; ++t2) {
        float bv = bias[g][w * 32 + t2 * 16 + tn];
#pragma unroll
        for (int i = 0; i < 4; ++i) uacc[g][t2][i] += bv;
      }
  }

  // ---------------- init c = 0 (regs + LDS buf0) ----------------
  float cr[2][4];
#pragma unroll
  for (int t2 = 0; t2 < 2; ++t2)
#pragma unroll
    for (int i = 0; i < 4; ++i) cr[t2][i] = 0.f;
  for (int idx = tid; idx < 16 * 136; idx += 256) {
    ((unsigned short*)cHi[0])[idx] = 0;
    ((unsigned short*)cLo[0])[idx] = 0;
  }
  __syncthreads();

  // ---------------- recurrence: steps 0..30 (no o-gate) ----------------
#pragma unroll 1
  for (int t = 0; t < NSTEP - 1; ++t) {
    const int rb = t & 1, wb = rb ^ 1;
    f32x4 zf[2], zi1[2], zi2[2];
#pragma unroll
    for (int t2 = 0; t2 < 2; ++t2) {
      zf[t2] = uacc[0][t2]; zi1[t2] = uacc[1][t2]; zi2[t2] = uacc[2][t2];
    }
#pragma unroll
    for (int kb = 0; kb < 4; ++kb) {
      bf16x8 ah = *(const bf16x8*)&cHi[rb][tn][kb * 32 + q * 8];
      bf16x8 al = *(const bf16x8*)&cLo[rb][tn][kb * 32 + q * 8];
#pragma unroll
      for (int t2 = 0; t2 < 2; ++t2) {
        int nb = w * 2 + t2;
        int fo = ((kb * 8 + nb) * 64 + lane) * 8;
        bf16x8 b0 = *(const bf16x8*)(Asw + fo);
        bf16x8 b1 = *(const bf16x8*)(Asw + 16384 + fo);
        bf16x8 b2 = *(const bf16x8*)(Asw + 32768 + fo);
        zf[t2]  = MFMA(ah, b0, zf[t2]);  zf[t2]  = MFMA(al, b0, zf[t2]);
        zi1[t2] = MFMA(ah, b1, zi1[t2]); zi1[t2] = MFMA(al, b1, zi1[t2]);
        zi2[t2] = MFMA(ah, b2, zi2[t2]); zi2[t2] = MFMA(al, b2, zi2[t2]);
      }
    }
#pragma unroll
    for (int t2 = 0; t2 < 2; ++t2)
#pragma unroll
      for (int i = 0; i < 4; ++i) {
        float fgate = sig_f(zf[t2][i]);
        float ig    = sig_f(zi1[t2][i]);
        float gg    = tanh_f(zi2[t2][i]);
        float cn = fmaf(cr[t2][i], fgate, ig * gg);
        cr[t2][i] = cn;
        unsigned short h = f2bf(cn);
        int row = q * 4 + i, col = w * 32 + t2 * 16 + tn;
        cHi[wb][row][col] = h;
        cLo[wb][row][col] = f2bf(cn - bf2f(h));
      }
    __syncthreads();
  }

  // ---------------- final step (t=31): + o-gate ----------------
  {
    const int rb = (NSTEP - 1) & 1;   // = 1
    f32x4 zf[2], zi1[2], zi2[2], zo[2];
#pragma unroll
    for (int t2 = 0; t2 < 2; ++t2) {
      zf[t2] = uacc[0][t2]; zi1[t2] = uacc[1][t2];
      zi2[t2] = uacc[2][t2]; zo[t2] = uacc[3][t2];
    }
#pragma unroll
    for (int kb = 0; kb < 4; ++kb) {
      bf16x8 ah = *(const bf16x8*)&cHi[rb][tn][kb * 32 + q * 8];
      bf16x8 al = *(const bf16x8*)&cLo[rb][tn][kb * 32 + q * 8];
#pragma unroll
      for (int t2 = 0; t2 < 2; ++t2) {
        int nb = w * 2 + t2;
        int fo = ((kb * 8 + nb) * 64 + lane) * 8;
        bf16x8 b0 = *(const bf16x8*)(Asw + fo);
        bf16x8 b1 = *(const bf16x8*)(Asw + 16384 + fo);
        bf16x8 b2 = *(const bf16x8*)(Asw + 32768 + fo);
        bf16x8 b3 = *(const bf16x8*)(Asw + 49152 + fo);
        zf[t2]  = MFMA(ah, b0, zf[t2]);  zf[t2]  = MFMA(al, b0, zf[t2]);
        zi1[t2] = MFMA(ah, b1, zi1[t2]); zi1[t2] = MFMA(al, b1, zi1[t2]);
        zi2[t2] = MFMA(ah, b2, zi2[t2]); zi2[t2] = MFMA(al, b2, zi2[t2]);
        zo[t2]  = MFMA(ah, b3, zo[t2]);  zo[t2]  = MFMA(al, b3, zo[t2]);
      }
    }
    __syncthreads();   // done reading cHi/cLo; uS.ep aliases old x region
#pragma unroll
    for (int t2 = 0; t2 < 2; ++t2)
#pragma unroll
      for (int i = 0; i < 4; ++i) {
        float fgate = sig_f(zf[t2][i]);
        float ig    = sig_f(zi1[t2][i]);
        float gg    = tanh_f(zi2[t2][i]);
        float cn = fmaf(cr[t2][i], fgate, ig * gg);
        cr[t2][i] = cn;
        float ov = sig_f(zo[t2][i]) * tanh_f(cn);
        int row = q * 4 + i, col = w * 32 + t2 * 16 + tn;
        uS.ep.o[row][col] = f2bf(ov);
      }
    __syncthreads();
  }

  // ---------------- epilogue: s = o @ Wc + bc, softmax over n ----------------
  {
    f32x4 sacc[2];
#pragma unroll
    for (int t2 = 0; t2 < 2; ++t2) sacc[t2] = (f32x4){0.f, 0.f, 0.f, 0.f};
#pragma unroll
    for (int kb = 0; kb < 4; ++kb) {
      bf16x8 a = *(const bf16x8*)&uS.ep.o[tn][kb * 32 + q * 8];
#pragma unroll
      for (int t2 = 0; t2 < 2; ++t2) {
        int nb = w * 2 + t2;
        bf16x8 b = *(const bf16x8*)(Wcsw + ((kb * 8 + nb) * 64 + lane) * 8);
        sacc[t2] = MFMA(a, b, sacc[t2]);
      }
    }
#pragma unroll
    for (int t2 = 0; t2 < 2; ++t2) {
      float bv = bc[w * 32 + t2 * 16 + tn];
#pragma unroll
      for (int i = 0; i < 4; ++i)
        uS.ep.s[q * 4 + i][w * 32 + t2 * 16 + tn] = sacc[t2][i] + bv;
    }
    __syncthreads();

    // wave w handles rows w*4 .. w*4+3; lane covers cols {lane, lane+64}
#pragma unroll
    for (int rr = 0; rr < 4; ++rr) {
      int r = w * 4 + rr;
      float v0 = uS.ep.s[r][lane];
      float v1 = uS.ep.s[r][lane + 64];
      float m = fmaxf(v0, v1);
#pragma unroll
      for (int off = 32; off; off >>= 1) m = fmaxf(m, __shfl_xor(m, off, 64));
      float e0 = __expf(v0 - m), e1 = __expf(v1 - m);
      float sm = e0 + e1;
#pragma unroll
      for (int off = 32; off; off >>= 1) sm += __shfl_xor(sm, off, 64);
      float inv = __builtin_amdgcn_rcpf(sm);
      size_t base = (size_t)(r0 + r) * 128;
      out[base + lane]      = e0 * inv;
      out[base + lane + 64] = e1 * inv;
    }

    // write final c (output 1), offset ROWS*128
#pragma unroll
    for (int t2 = 0; t2 < 2; ++t2)
#pragma unroll
      for (int i = 0; i < 4; ++i) {
        int row = q * 4 + i, col = w * 32 + t2 * 16 + tn;
        out[(size_t)ROWS * 128 + (size_t)(r0 + row) * 128 + col] = cr[t2][i];
      }
  }
}

extern "C" void kernel_launch(void* const* d_in, const int* in_sizes, int n_in,
                              void* d_out, int out_size, void* d_ws, size_t ws_size,
                              hipStream_t stream) {
  const float* x   = (const float*)d_in[0];
  const float* Wf  = (const float*)d_in[1];
  const float* bf_ = (const float*)d_in[2];
  const float* Wi1 = (const float*)d_in[3];
  const float* bi1 = (const float*)d_in[4];
  const float* Wi2 = (const float*)d_in[5];
  const float* bi2 = (const float*)d_in[6];
  const float* Wo  = (const float*)d_in[7];
  const float* bo  = (const float*)d_in[8];
  const float* Wc  = (const float*)d_in[9];
  const float* bc  = (const float*)d_in[10];
  unsigned short* ws = (unsigned short*)d_ws;
  float* out = (float*)d_out;

  hipLaunchKernelGGL(prep_kernel, dim3(WSTOT / 256), dim3(256), 0, stream,
                     Wf, Wi1, Wi2, Wo, Wc, ws);
  hipLaunchKernelGGL(lstm_kernel, dim3(ROWS / RPB), dim3(256), 0, stream,
                     x, bf_, bi1, bi2, bo, bc, ws, out);
}

// Round 2
// 179.725 us; speedup vs baseline: 1.5031x; 1.5031x over previous
//
#include <hip/hip_runtime.h>
#include <stdint.h>

// Problem constants
#define ROWS  16384   // B*T = 512*32
#define CELL  128
#define INF   512
#define RPB   16      // rows per block
#define NSTEP 32

typedef _Float16 f16x8 __attribute__((ext_vector_type(8)));
typedef _Float16 f16x4 __attribute__((ext_vector_type(4)));
typedef float    f32x4 __attribute__((ext_vector_type(4)));

#define MFMA16(a, b, c) __builtin_amdgcn_mfma_f32_16x16x32_f16((a), (b), (c), 0, 0, 0)

// ws layout (f16 elems):
//   A_sw[g]  at g*16384          (g=0..3: Wf,Wi1,Wi2,Wo rows 0..127 -> cell part)
//   Xw_sw[g] at 65536 + g*65536  (rows 128..639 -> x part)
//   Wc_sw    at 327680
#define AOFF  0
#define XOFF  65536
#define WCOFF 327680
#define WSTOT 344064

__device__ __forceinline__ unsigned short f2h_bits(float f) {
  _Float16 h = (_Float16)f;   // v_cvt_f16_f32, RNE
  return *(unsigned short*)&h;
}
__device__ __forceinline__ float sig_f(float z) {
  return __builtin_amdgcn_rcpf(1.f + __expf(-z));
}
__device__ __forceinline__ float tanh_f(float z) {
  return 1.f - 2.f * __builtin_amdgcn_rcpf(__expf(2.f * z) + 1.f);
}

// Swizzle weights to f16 MFMA B-fragment order:
// dst[((kb*8+nb)*64 + lane)*8 + j] = W[kb*32 + (lane>>4)*8 + j][nb*16 + (lane&15)]
__global__ __launch_bounds__(256) void prep_kernel(
    const float* __restrict__ Wf, const float* __restrict__ Wi1,
    const float* __restrict__ Wi2, const float* __restrict__ Wo,
    const float* __restrict__ Wc, unsigned short* __restrict__ ws) {
  int id = blockIdx.x * blockDim.x + threadIdx.x;
  if (id >= WSTOT) return;
  const float* Wg[4] = {Wf, Wi1, Wi2, Wo};
  if (id < XOFF) {                       // cell-part A matrices (k = 0..127)
    int g = id >> 14, r = id & 16383;
    int j = r & 7, lane = (r >> 3) & 63, nb = (r >> 9) & 7, kb = r >> 12;
    int k = kb * 32 + ((lane >> 4) << 3) + j;
    int n = nb * 16 + (lane & 15);
    ws[id] = f2h_bits(Wg[g][k * CELL + n]);
  } else if (id < WCOFF) {               // x-part (k = 0..511, W row 128+k)
    int t = id - XOFF;
    int g = t >> 16, r = t & 65535;
    int j = r & 7, lane = (r >> 3) & 63, nb = (r >> 9) & 7, kb = r >> 12;
    int k = kb * 32 + ((lane >> 4) << 3) + j;
    int n = nb * 16 + (lane & 15);
    ws[id] = f2h_bits(Wg[g][(CELL + k) * CELL + n]);
  } else {                               // Wc [128][128]
    int r = id - WCOFF;
    int j = r & 7, lane = (r >> 3) & 63, nb = (r >> 9) & 7, kb = r >> 12;
    int k = kb * 32 + ((lane >> 4) << 3) + j;
    int n = nb * 16 + (lane & 15);
    ws[id] = f2h_bits(Wc[k * CELL + n]);
  }
}

// 3 blocks/CU: LDS 29952 B, VGPR capped by (256,3). Weights for the 3
// recurrent gates live in 96 VGPRs/wave; the 31-step loop touches only LDS.
__global__ __launch_bounds__(256, 3) void lstm_kernel(
    const float* __restrict__ x,
    const float* __restrict__ bf_, const float* __restrict__ bi1,
    const float* __restrict__ bi2, const float* __restrict__ bo,
    const float* __restrict__ bc,
    const unsigned short* __restrict__ ws, float* __restrict__ out) {

  __shared__ union {
    _Float16 xs[16][264];                    // one 256-col staging chunk (8448 B)
    struct {
      _Float16 o[16][136];                   // 4352 B
      float    s[16][132];                   // 8448 B
    } ep;
  } uS;                                      // 12800 B
  __shared__ _Float16 cF[2][16][136];        // 8704 B, double-buffered c (f16)
  __shared__ float    uo[16][132];           // 8448 B, o-gate preactivation

  const int tid  = threadIdx.x;
  const int lane = tid & 63;
  const int w    = tid >> 6;     // wave 0..3, owns cols [w*32, w*32+32)
  const int q    = lane >> 4;    // 0..3
  const int tn   = lane & 15;
  const int r0   = blockIdx.x * RPB;

  const _Float16* Aw  = (const _Float16*)ws + AOFF;
  const _Float16* Xw  = (const _Float16*)ws + XOFF;
  const _Float16* Wcw = (const _Float16*)ws + WCOFF;

  // ---------------- precompute u_g = x @ Wg[128:,:] (chunked x staging) ----
  f32x4 uacc[4][2];
#pragma unroll
  for (int g = 0; g < 4; ++g)
#pragma unroll
    for (int t2 = 0; t2 < 2; ++t2) uacc[g][t2] = (f32x4){0.f, 0.f, 0.f, 0.f};

  const float* xbase = x + (size_t)r0 * INF;
#pragma unroll 1
  for (int ch = 0; ch < 2; ++ch) {
    if (ch) __syncthreads();               // done reading previous chunk
#pragma unroll
    for (int i = 0; i < 4; ++i) {
      int flat = tid + i * 256;            // 1024 float4 slots = 16 rows * 64
      int row = flat >> 6, c4 = flat & 63;
      const float4 v = ((const float4*)(xbase + (size_t)row * INF + ch * 256))[c4];
      f16x4 h = {(_Float16)v.x, (_Float16)v.y, (_Float16)v.z, (_Float16)v.w};
      *(f16x4*)&uS.xs[row][c4 * 4] = h;
    }
    __syncthreads();
#pragma unroll 2
    for (int kb8 = 0; kb8 < 8; ++kb8) {
      f16x8 a = *(const f16x8*)&uS.xs[tn][kb8 * 32 + q * 8];
      int kb = ch * 8 + kb8;
#pragma unroll
      for (int g = 0; g < 4; ++g) {
#pragma unroll
        for (int t2 = 0; t2 < 2; ++t2) {
          f16x8 b = *(const f16x8*)(Xw + g * 65536 + ((kb * 8 + w * 2 + t2) * 64 + lane) * 8);
          uacc[g][t2] = MFMA16(a, b, uacc[g][t2]);
        }
      }
    }
  }
  // biases; park o-gate preactivation in LDS (frees uacc[3] for the loop)
  {
    const float* bias[4] = {bf_, bi1, bi2, bo};
#pragma unroll
    for (int g = 0; g < 3; ++g)
#pragma unroll
      for (int t2 = 0; t2 < 2; ++t2) {
        float bv = bias[g][w * 32 + t2 * 16 + tn];
#pragma unroll
        for (int i = 0; i < 4; ++i) uacc[g][t2][i] += bv;
      }
#pragma unroll
    for (int t2 = 0; t2 < 2; ++t2) {
      int col = w * 32 + t2 * 16 + tn;
      float bv = bo[col];
#pragma unroll
      for (int i = 0; i < 4; ++i) uo[q * 4 + i][col] = uacc[3][t2][i] + bv;
    }
  }

  // ---------------- hoist recurrent-gate weights into registers ----------
  f16x8 wr[3][4][2];   // [gate f,i1,i2][kb][t2] -> 96 VGPRs
#pragma unroll
  for (int g = 0; g < 3; ++g)
#pragma unroll
    for (int kb = 0; kb < 4; ++kb)
#pragma unroll
      for (int t2 = 0; t2 < 2; ++t2)
        wr[g][kb][t2] = *(const f16x8*)(Aw + g * 16384 + ((kb * 8 + w * 2 + t2) * 64 + lane) * 8);

  // ---------------- step 0: c_prev = 0 => z = u -------------------------
  float cr[2][4];
#pragma unroll
  for (int t2 = 0; t2 < 2; ++t2)
#pragma unroll
    for (int i = 0; i < 4; ++i) {
      float ig = sig_f(uacc[1][t2][i]);
      float gg = tanh_f(uacc[2][t2][i]);
      float c0 = ig * gg;
      cr[t2][i] = c0;
      cF[0][q * 4 + i][w * 32 + t2 * 16 + tn] = (_Float16)c0;
    }
  __syncthreads();

  // ---------------- recurrence: steps 1..30 -----------------------------
#pragma unroll 1
  for (int t = 1; t < NSTEP - 1; ++t) {
    const int rb = (t + 1) & 1, wb = t & 1;
    f32x4 zf[2], zi1[2], zi2[2];
#pragma unroll
    for (int t2 = 0; t2 < 2; ++t2) {
      zf[t2] = uacc[0][t2]; zi1[t2] = uacc[1][t2]; zi2[t2] = uacc[2][t2];
    }
#pragma unroll
    for (int kb = 0; kb < 4; ++kb) {
      f16x8 a = *(const f16x8*)&cF[rb][tn][kb * 32 + q * 8];
#pragma unroll
      for (int t2 = 0; t2 < 2; ++t2) {
        zf[t2]  = MFMA16(a, wr[0][kb][t2], zf[t2]);
        zi1[t2] = MFMA16(a, wr[1][kb][t2], zi1[t2]);
        zi2[t2] = MFMA16(a, wr[2][kb][t2], zi2[t2]);
      }
    }
#pragma unroll
    for (int t2 = 0; t2 < 2; ++t2)
#pragma unroll
      for (int i = 0; i < 4; ++i) {
        float fgate = sig_f(zf[t2][i]);
        float ig    = sig_f(zi1[t2][i]);
        float gg    = tanh_f(zi2[t2][i]);
        float cn = fmaf(cr[t2][i], fgate, ig * gg);
        cr[t2][i] = cn;
        cF[wb][q * 4 + i][w * 32 + t2 * 16 + tn] = (_Float16)cn;
      }
    __syncthreads();
  }

  // ---------------- final step (t=31): + o-gate -------------------------
  {
    // reads cF[0] (written at t=30, wb=0)
    f32x4 zf[2], zi1[2], zi2[2], zo[2];
#pragma unroll
    for (int t2 = 0; t2 < 2; ++t2) {
      zf[t2] = uacc[0][t2]; zi1[t2] = uacc[1][t2]; zi2[t2] = uacc[2][t2];
      int col = w * 32 + t2 * 16 + tn;
#pragma unroll
      for (int i = 0; i < 4; ++i) zo[t2][i] = uo[q * 4 + i][col];
    }
#pragma unroll
    for (int kb = 0; kb < 4; ++kb) {
      f16x8 a = *(const f16x8*)&cF[0][tn][kb * 32 + q * 8];
#pragma unroll
      for (int t2 = 0; t2 < 2; ++t2) {
        f16x8 bo_frag = *(const f16x8*)(Aw + 3 * 16384 + ((kb * 8 + w * 2 + t2) * 64 + lane) * 8);
        zf[t2]  = MFMA16(a, wr[0][kb][t2], zf[t2]);
        zi1[t2] = MFMA16(a, wr[1][kb][t2], zi1[t2]);
        zi2[t2] = MFMA16(a, wr[2][kb][t2], zi2[t2]);
        zo[t2]  = MFMA16(a, bo_frag, zo[t2]);
      }
    }
#pragma unroll
    for (int t2 = 0; t2 < 2; ++t2)
#pragma unroll
      for (int i = 0; i < 4; ++i) {
        float fgate = sig_f(zf[t2][i]);
        float ig    = sig_f(zi1[t2][i]);
        float gg    = tanh_f(zi2[t2][i]);
        float cn = fmaf(cr[t2][i], fgate, ig * gg);
        cr[t2][i] = cn;
        float ov = sig_f(zo[t2][i]) * tanh_f(cn);
        uS.ep.o[q * 4 + i][w * 32 + t2 * 16 + tn] = (_Float16)ov;  // aliases dead xs
      }
    __syncthreads();
  }

  // ---------------- epilogue: s = o @ Wc + bc, softmax ------------------
  {
    f32x4 sacc[2];
#pragma unroll
    for (int t2 = 0; t2 < 2; ++t2) sacc[t2] = (f32x4){0.f, 0.f, 0.f, 0.f};
#pragma unroll
    for (int kb = 0; kb < 4; ++kb) {
      f16x8 a = *(const f16x8*)&uS.ep.o[tn][kb * 32 + q * 8];
#pragma unroll
      for (int t2 = 0; t2 < 2; ++t2) {
        f16x8 b = *(const f16x8*)(Wcw + ((kb * 8 + w * 2 + t2) * 64 + lane) * 8);
        sacc[t2] = MFMA16(a, b, sacc[t2]);
      }
    }
#pragma unroll
    for (int t2 = 0; t2 < 2; ++t2) {
      int col = w * 32 + t2 * 16 + tn;
      float bv = bc[col];
#pragma unroll
      for (int i = 0; i < 4; ++i)
        uS.ep.s[q * 4 + i][col] = sacc[t2][i] + bv;
    }
    __syncthreads();

    // wave w reduces rows w*4 .. w*4+3; lane covers cols {lane, lane+64}
#pragma unroll
    for (int rr = 0; rr < 4; ++rr) {
      int r = w * 4 + rr;
      float v0 = uS.ep.s[r][lane];
      float v1 = uS.ep.s[r][lane + 64];
      float m = fmaxf(v0, v1);
#pragma unroll
      for (int off = 32; off; off >>= 1) m = fmaxf(m, __shfl_xor(m, off, 64));
      float e0 = __expf(v0 - m), e1 = __expf(v1 - m);
      float sm = e0 + e1;
#pragma unroll
      for (int off = 32; off; off >>= 1) sm += __shfl_xor(sm, off, 64);
      float inv = __builtin_amdgcn_rcpf(sm);
      size_t base = (size_t)(r0 + r) * 128;
      out[base + lane]      = e0 * inv;
      out[base + lane + 64] = e1 * inv;
    }

    // final c (output 1) at offset ROWS*128
#pragma unroll
    for (int t2 = 0; t2 < 2; ++t2)
#pragma unroll
      for (int i = 0; i < 4; ++i) {
        int row = q * 4 + i, col = w * 32 + t2 * 16 + tn;
        out[(size_t)ROWS * 128 + (size_t)(r0 + row) * 128 + col] = cr[t2][i];
      }
  }
}

extern "C" void kernel_launch(void* const* d_in, const int* in_sizes, int n_in,
                              void* d_out, int out_size, void* d_ws, size_t ws_size,
                              hipStream_t stream) {
  const float* x   = (const float*)d_in[0];
  const float* Wf  = (const float*)d_in[1];
  const float* bf_ = (const float*)d_in[2];
  const float* Wi1 = (const float*)d_in[3];
  const float* bi1 = (const float*)d_in[4];
  const float* Wi2 = (const float*)d_in[5];
  const float* bi2 = (const float*)d_in[6];
  const float* Wo  = (const float*)d_in[7];
  const float* bo  = (const float*)d_in[8];
  const float* Wc  = (const float*)d_in[9];
  const float* bc  = (const float*)d_in[10];
  unsigned short* ws = (unsigned short*)d_ws;
  float* out = (float*)d_out;

  hipLaunchKernelGGL(prep_kernel, dim3((WSTOT + 255) / 256), dim3(256), 0, stream,
                     Wf, Wi1, Wi2, Wo, Wc, ws);
  hipLaunchKernelGGL(lstm_kernel, dim3(ROWS / RPB), dim3(256), 0, stream,
                     x, bf_, bi1, bi2, bo, bc, ws, out);
}

// Round 3
// 177.386 us; speedup vs baseline: 1.5230x; 1.0132x over previous
//
#include <hip/hip_runtime.h>
#include <stdint.h>

// Problem constants
#define ROWS  16384   // B*T = 512*32
#define CELL  128
#define INF   512
#define RPB   32      // rows per block
#define NSTEP 32

typedef _Float16 f16x8 __attribute__((ext_vector_type(8)));
typedef _Float16 f16x4 __attribute__((ext_vector_type(4)));
typedef float    f32x16 __attribute__((ext_vector_type(16)));

#define MFMA32(a, b, c) __builtin_amdgcn_mfma_f32_32x32x16_f16((a), (b), (c), 0, 0, 0)

// ws layout (f16 elems), all in 32x32x16 B-fragment order:
//   A_sw[g]  at g*16384          (g=0..3: Wf,Wi1,Wi2,Wo rows 0..127, cell part)
//   Xw_sw[g] at 65536 + g*65536  (rows 128..639, x part)
//   Wc_sw    at 327680
// frag addr: ((ks*4 + nb)*64 + lane)*8 + j  <->  W[ks*16 + (lane>>5)*8 + j][nb*32 + (lane&31)]
#define AOFF  0
#define XOFF  65536
#define WCOFF 327680
#define WSTOT 344064

__device__ __forceinline__ unsigned short f2h_bits(float f) {
  _Float16 h = (_Float16)f;
  return *(unsigned short*)&h;
}
__device__ __forceinline__ float sig_f(float z) {
  return __builtin_amdgcn_rcpf(1.f + __expf(-z));
}
__device__ __forceinline__ float tanh_f(float z) {
  return 1.f - 2.f * __builtin_amdgcn_rcpf(__expf(2.f * z) + 1.f);
}

__global__ __launch_bounds__(256) void prep_kernel(
    const float* __restrict__ Wf, const float* __restrict__ Wi1,
    const float* __restrict__ Wi2, const float* __restrict__ Wo,
    const float* __restrict__ Wc, unsigned short* __restrict__ ws) {
  int id = blockIdx.x * blockDim.x + threadIdx.x;
  if (id >= WSTOT) return;
  const float* Wg[4] = {Wf, Wi1, Wi2, Wo};
  if (id < XOFF) {                       // cell-part (k = 0..127)
    int g = id >> 14, r = id & 16383;
    int j = r & 7, lane = (r >> 3) & 63, tile = r >> 9;   // tile 0..31
    int nb = tile & 3, ks = tile >> 2;
    int k = ks * 16 + ((lane >> 5) << 3) + j;
    int n = nb * 32 + (lane & 31);
    ws[id] = f2h_bits(Wg[g][k * CELL + n]);
  } else if (id < WCOFF) {               // x-part (k = 0..511 -> W row 128+k)
    int t = id - XOFF;
    int g = t >> 16, r = t & 65535;
    int j = r & 7, lane = (r >> 3) & 63, tile = r >> 9;   // tile 0..127
    int nb = tile & 3, ks = tile >> 2;
    int k = ks * 16 + ((lane >> 5) << 3) + j;
    int n = nb * 32 + (lane & 31);
    ws[id] = f2h_bits(Wg[g][(CELL + k) * CELL + n]);
  } else {                               // Wc [128][128]
    int r = id - WCOFF;
    int j = r & 7, lane = (r >> 3) & 63, tile = r >> 9;
    int nb = tile & 3, ks = tile >> 2;
    int k = ks * 16 + ((lane >> 5) << 3) + j;
    int n = nb * 32 + (lane & 31);
    ws[id] = f2h_bits(Wc[k * CELL + n]);
  }
}

// 2 blocks/CU (grid 512 = 2/CU, all resident). 32 rows/block, each wave owns a
// 32-col slice; recurrent weights (3 gates) in 96 VGPRs/wave; c LDS round trip
// with 1 barrier/step.
__global__ __launch_bounds__(256, 2) void lstm_kernel(
    const float* __restrict__ x,
    const float* __restrict__ bf_, const float* __restrict__ bi1,
    const float* __restrict__ bi2, const float* __restrict__ bo,
    const float* __restrict__ bc,
    const unsigned short* __restrict__ ws, float* __restrict__ out) {

  __shared__ union {
    _Float16 xs[32][264];                    // 16896 B, x staging chunk
    struct {
      _Float16 o[32][136];                   // 8704 B
      float    s[32][132];                   // 16896 B
    } ep;                                    // 25600 B
  } uS;
  __shared__ _Float16 cF[2][32][136];        // 17408 B, double-buffered c
  __shared__ float    uo[32][132];           // 16896 B, o-gate preactivation

  const int tid  = threadIdx.x;
  const int lane = tid & 63;
  const int w    = tid >> 6;     // wave 0..3, owns cols [w*32, w*32+32)
  const int n    = lane & 31;
  const int l5   = lane >> 5;
  const int col  = w * 32 + n;   // this lane's output column
  const int r0   = blockIdx.x * RPB;

  const _Float16* Aw  = (const _Float16*)ws + AOFF;
  const _Float16* Xw  = (const _Float16*)ws + XOFF;
  const _Float16* Wcw = (const _Float16*)ws + WCOFF;

  // ---------------- precompute u_g = x @ Wg[128:,:] (2 chunks of 256) -----
  f32x16 u[4];
#pragma unroll
  for (int g = 0; g < 4; ++g)
#pragma unroll
    for (int i = 0; i < 16; ++i) u[g][i] = 0.f;

  const float* xbase = x + (size_t)r0 * INF;
#pragma unroll 1
  for (int ch = 0; ch < 2; ++ch) {
    if (ch) __syncthreads();
#pragma unroll
    for (int i = 0; i < 8; ++i) {
      int flat = tid + i * 256;            // 2048 = 32 rows * 64 float4
      int row = flat >> 6, c4 = flat & 63;
      const float4 v = ((const float4*)(xbase + (size_t)row * INF + ch * 256))[c4];
      f16x4 h = {(_Float16)v.x, (_Float16)v.y, (_Float16)v.z, (_Float16)v.w};
      *(f16x4*)&uS.xs[row][c4 * 4] = h;
    }
    __syncthreads();
#pragma unroll 2
    for (int ks8 = 0; ks8 < 16; ++ks8) {
      f16x8 a = *(const f16x8*)&uS.xs[n][ks8 * 16 + l5 * 8];
      int ks = ch * 16 + ks8;
#pragma unroll
      for (int g = 0; g < 4; ++g) {
        f16x8 b = *(const f16x8*)(Xw + g * 65536 + ((ks * 4 + w) * 64 + lane) * 8);
        u[g] = MFMA32(a, b, u[g]);
      }
    }
  }
  // biases into u[0..2]; o preact (u[3]+bo) parked in LDS
  {
    float b0 = bf_[col], b1 = bi1[col], b2 = bi2[col], b3 = bo[col];
#pragma unroll
    for (int reg = 0; reg < 16; ++reg) {
      u[0][reg] += b0; u[1][reg] += b1; u[2][reg] += b2;
      int r = (reg & 3) + 8 * (reg >> 2) + 4 * l5;
      uo[r][col] = u[3][reg] + b3;
    }
  }

  // ---------------- recurrent-gate weights -> registers -------------------
  f16x8 wr[3][8];   // [gate f,i1,i2][ks] -> 96 VGPRs
#pragma unroll
  for (int g = 0; g < 3; ++g)
#pragma unroll
    for (int ks = 0; ks < 8; ++ks)
      wr[g][ks] = *(const f16x8*)(Aw + g * 16384 + ((ks * 4 + w) * 64 + lane) * 8);

  // ---------------- step 0: c_prev = 0 => z = u ---------------------------
  f32x16 cr;
#pragma unroll
  for (int reg = 0; reg < 16; ++reg) {
    float ig = sig_f(u[1][reg]);
    float gg = tanh_f(u[2][reg]);
    float c0 = ig * gg;
    cr[reg] = c0;
    int r = (reg & 3) + 8 * (reg >> 2) + 4 * l5;
    cF[0][r][col] = (_Float16)c0;
  }
  __syncthreads();

  // ---------------- recurrence: steps 1..30 -------------------------------
#pragma unroll 1
  for (int t = 1; t < NSTEP - 1; ++t) {
    const int rb = (t + 1) & 1, wb = t & 1;
    f16x8 a[8];
#pragma unroll
    for (int ks = 0; ks < 8; ++ks)
      a[ks] = *(const f16x8*)&cF[rb][n][ks * 16 + l5 * 8];
    f32x16 zf = u[0], zi1 = u[1], zi2 = u[2];
#pragma unroll
    for (int ks = 0; ks < 8; ++ks) {
      zf  = MFMA32(a[ks], wr[0][ks], zf);
      zi1 = MFMA32(a[ks], wr[1][ks], zi1);
      zi2 = MFMA32(a[ks], wr[2][ks], zi2);
    }
#pragma unroll
    for (int reg = 0; reg < 16; ++reg) {
      float fg = sig_f(zf[reg]);
      float ig = sig_f(zi1[reg]);
      float gg = tanh_f(zi2[reg]);
      float cn = fmaf(cr[reg], fg, ig * gg);
      cr[reg] = cn;
      int r = (reg & 3) + 8 * (reg >> 2) + 4 * l5;
      cF[wb][r][col] = (_Float16)cn;
    }
    __syncthreads();
  }

  // ---------------- final step (t=31): + o-gate ---------------------------
  {
    // reads cF[0] (written at t=30)
    f16x8 a[8];
#pragma unroll
    for (int ks = 0; ks < 8; ++ks)
      a[ks] = *(const f16x8*)&cF[0][n][ks * 16 + l5 * 8];
    f32x16 zf = u[0], zi1 = u[1], zi2 = u[2], zo;
#pragma unroll
    for (int reg = 0; reg < 16; ++reg) {
      int r = (reg & 3) + 8 * (reg >> 2) + 4 * l5;
      zo[reg] = uo[r][col];
    }
#pragma unroll
    for (int ks = 0; ks < 8; ++ks) {
      f16x8 bo_frag = *(const f16x8*)(Aw + 3 * 16384 + ((ks * 4 + w) * 64 + lane) * 8);
      zf  = MFMA32(a[ks], wr[0][ks], zf);
      zi1 = MFMA32(a[ks], wr[1][ks], zi1);
      zi2 = MFMA32(a[ks], wr[2][ks], zi2);
      zo  = MFMA32(a[ks], bo_frag, zo);
    }
    __syncthreads();   // all reads of cF/xs done; uS.ep becomes live
#pragma unroll
    for (int reg = 0; reg < 16; ++reg) {
      float fg = sig_f(zf[reg]);
      float ig = sig_f(zi1[reg]);
      float gg = tanh_f(zi2[reg]);
      float cn = fmaf(cr[reg], fg, ig * gg);
      cr[reg] = cn;
      float ov = sig_f(zo[reg]) * tanh_f(cn);
      int r = (reg & 3) + 8 * (reg >> 2) + 4 * l5;
      uS.ep.o[r][col] = (_Float16)ov;
    }
    __syncthreads();
  }

  // ---------------- epilogue: s = o @ Wc + bc, softmax --------------------
  {
    f32x16 sacc;
#pragma unroll
    for (int i = 0; i < 16; ++i) sacc[i] = 0.f;
#pragma unroll
    for (int ks = 0; ks < 8; ++ks) {
      f16x8 a = *(const f16x8*)&uS.ep.o[n][ks * 16 + l5 * 8];
      f16x8 b = *(const f16x8*)(Wcw + ((ks * 4 + w) * 64 + lane) * 8);
      sacc = MFMA32(a, b, sacc);
    }
    float bv = bc[col];
#pragma unroll
    for (int reg = 0; reg < 16; ++reg) {
      int r = (reg & 3) + 8 * (reg >> 2) + 4 * l5;
      uS.ep.s[r][col] = sacc[reg] + bv;
    }
    __syncthreads();

    // wave w reduces rows w*8 .. w*8+7; lane covers cols {lane, lane+64}
#pragma unroll
    for (int rr = 0; rr < 8; ++rr) {
      int r = w * 8 + rr;
      float v0 = uS.ep.s[r][lane];
      float v1 = uS.ep.s[r][lane + 64];
      float m = fmaxf(v0, v1);
#pragma unroll
      for (int off = 32; off; off >>= 1) m = fmaxf(m, __shfl_xor(m, off, 64));
      float e0 = __expf(v0 - m), e1 = __expf(v1 - m);
      float sm = e0 + e1;
#pragma unroll
      for (int off = 32; off; off >>= 1) sm += __shfl_xor(sm, off, 64);
      float inv = __builtin_amdgcn_rcpf(sm);
      size_t base = (size_t)(r0 + r) * 128;
      out[base + lane]      = e0 * inv;
      out[base + lane + 64] = e1 * inv;
    }

    // final c (output 1) at offset ROWS*128
#pragma unroll
    for (int reg = 0; reg < 16; ++reg) {
      int r = (reg & 3) + 8 * (reg >> 2) + 4 * l5;
      out[(size_t)ROWS * 128 + (size_t)(r0 + r) * 128 + col] = cr[reg];
    }
  }
}

extern "C" void kernel_launch(void* const* d_in, const int* in_sizes, int n_in,
                              void* d_out, int out_size, void* d_ws, size_t ws_size,
                              hipStream_t stream) {
  const float* x   = (const float*)d_in[0];
  const float* Wf  = (const float*)d_in[1];
  const float* bf_ = (const float*)d_in[2];
  const float* Wi1 = (const float*)d_in[3];
  const float* bi1 = (const float*)d_in[4];
  const float* Wi2 = (const float*)d_in[5];
  const float* bi2 = (const float*)d_in[6];
  const float* Wo  = (const float*)d_in[7];
  const float* bo  = (const float*)d_in[8];
  const float* Wc  = (const float*)d_in[9];
  const float* bc  = (const float*)d_in[10];
  unsigned short* ws = (unsigned short*)d_ws;
  float* out = (float*)d_out;

  hipLaunchKernelGGL(prep_kernel, dim3((WSTOT + 255) / 256), dim3(256), 0, stream,
                     Wf, Wi1, Wi2, Wo, Wc, ws);
  hipLaunchKernelGGL(lstm_kernel, dim3(ROWS / RPB), dim3(256), 0, stream,
                     x, bf_, bi1, bi2, bo, bc, ws, out);
}